// Round 10
// baseline (443.011 us; speedup 1.0000x reference)
//
#include <hip/hip_runtime.h>

typedef unsigned short u16;
using f32x4  = __attribute__((ext_vector_type(4))) float;
using bf16x8 = __attribute__((ext_vector_type(8))) __bf16;

// ---------- bf16 helpers ----------
__device__ __forceinline__ u16 f2bf(float f) {
  unsigned u = __builtin_bit_cast(unsigned, f);
  u += 0x7FFFu + ((u >> 16) & 1u);
  return (u16)(u >> 16);
}
__device__ __forceinline__ float bf2f(u16 h) {
  unsigned u = ((unsigned)h) << 16;
  return __builtin_bit_cast(float, u);
}

// two floats -> packed (hi bf16x2, lo bf16x2); RNE hi, trunc lo.
__device__ __forceinline__ void split2(float f0, float f1, unsigned& hi, unsigned& lo) {
  unsigned u0 = __builtin_bit_cast(unsigned, f0);
  unsigned u1 = __builtin_bit_cast(unsigned, f1);
  unsigned r0 = u0 + (0x7FFFu + ((u0 >> 16) & 1u));
  unsigned r1 = u1 + (0x7FFFu + ((u1 >> 16) & 1u));
  hi = (r0 >> 16) | (r1 & 0xFFFF0000u);
  float h0 = __builtin_bit_cast(float, r0 & 0xFFFF0000u);
  float h1 = __builtin_bit_cast(float, r1 & 0xFFFF0000u);
  unsigned l0 = __builtin_bit_cast(unsigned, f0 - h0);
  unsigned l1 = __builtin_bit_cast(unsigned, f1 - h1);
  lo = (l0 >> 16) | (l1 & 0xFFFF0000u);
}

// cvt_pk-based split (R5): 6 VALU ops vs ~11. hi = RNE pair; lo = RNE residual.
__device__ __forceinline__ void split2_pk(float f0, float f1, unsigned& hi, unsigned& lo) {
  unsigned h;
  asm("v_cvt_pk_bf16_f32 %0, %1, %2" : "=v"(h) : "v"(f0), "v"(f1));
  const float h0 = __builtin_bit_cast(float, h << 16);
  const float h1 = __builtin_bit_cast(float, h & 0xFFFF0000u);
  unsigned l;
  asm("v_cvt_pk_bf16_f32 %0, %1, %2" : "=v"(l) : "v"(f0 - h0), "v"(f1 - h1));
  hi = h; lo = l;
}

// async global->LDS, 16B/lane; LDS dest MUST be wave-uniform base + lane*16
__device__ __forceinline__ void gload_lds16(const void* g, void* l) {
  __builtin_amdgcn_global_load_lds((__attribute__((address_space(1))) void*)g,
                                   (__attribute__((address_space(3))) void*)l,
                                   16, 0, 0);
}

// ---------- split W1+W2 -> stacked (bf16 hi, bf16 lo), one launch (R9) ----------
__global__ __launch_bounds__(256) void splitW_kernel(
    const float* __restrict__ W1, const float* __restrict__ W2,
    u16* __restrict__ hi, u16* __restrict__ lo, int n4each)
{
  const size_t t = (size_t)blockIdx.x * 256 + threadIdx.x;
  const float4 v = (t < (size_t)n4each) ? ((const float4*)W1)[t]
                                        : ((const float4*)W2)[t - n4each];
  uint2 hp, lp;
  split2(v.x, v.y, hp.x, lp.x);
  split2(v.z, v.w, hp.y, lp.y);
  ((uint2*)hi)[t] = hp;
  ((uint2*)lo)[t] = lp;
}

// =====================================================================
// GEMM1: h[:,0:512]=x1@W1^T+b1, h[:,512:1024]=x2@W2^T+b2 (W stacked 1024xK)
// split-K=2 (R8), 2x2 wave layout, split2_pk, counted-vmcnt (T4) +
// setprio (T5), double-buffered 64 KB LDS. grid (32,8,2), block 256.
// =====================================================================
__global__ __launch_bounds__(256) void gemm1_k(
    const float* __restrict__ x1, const float* __restrict__ x2,
    const u16* __restrict__ WH, const u16* __restrict__ WL,
    const float* __restrict__ b1, const float* __restrict__ b2,
    float* __restrict__ hp0, float* __restrict__ hp1)
{
  constexpr int K = 4096, NC = 1024, KC = 2048, NT = KC / 32;
  __shared__ __align__(16) float lA[2][128 * 32];   // 16 KB x2
  __shared__ __align__(16) u16 lBh[2][128 * 32];    // 8 KB x2
  __shared__ __align__(16) u16 lBl[2][128 * 32];    // 8 KB x2

  const int tid  = threadIdx.x;
  const int lane = tid & 63;
  const int wave = tid >> 6;
  const int wr   = wave >> 1, wc = wave & 1;   // 2x2: wave owns 64x64
  const int quad = lane >> 4;
  const int l16  = lane & 15;

  const int m0    = blockIdx.x * 128;
  const int n0    = blockIdx.y * 128;
  const int batch = (n0 >= 512);
  const float* Ag   = batch ? x2 : x1;
  const float* bias = batch ? b2 : b1;
  const int z = blockIdx.z;
  float* hp = (z == 0) ? hp0 : hp1;
  const int k00 = z * KC;

  // staging maps (LDS dest linear in tid*16 -> DMA-legal)
  const int rA = tid >> 3, cA = tid & 7;  // A: 4 rounds x 32 rows, 8 chunks/row
  const int rB = tid >> 2, cB = tid & 3;  // B: 2 rounds x 64 rows, 4 chunks/row

  auto stage = [&](int buf, int kt) {   // 8 VMEM instrs per wave
    const int ko = k00 + kt * 32;
#pragma unroll
    for (int t = 0; t < 4; ++t) {
      const int r  = t * 32 + rA;
      const int cs = (cA + r) & 7;                 // source-chunk swizzle
      gload_lds16(Ag + (size_t)(m0 + r) * K + ko + cs * 4,
                  (char*)lA[buf] + t * 4096 + tid * 16);
    }
#pragma unroll
    for (int t = 0; t < 2; ++t) {
      const int r  = t * 64 + rB;
      const int cs = (cB + (r >> 1)) & 3;
      gload_lds16(WH + (size_t)(n0 + r) * K + ko + cs * 8,
                  (char*)lBh[buf] + t * 4096 + tid * 16);
      gload_lds16(WL + (size_t)(n0 + r) * K + ko + cs * 8,
                  (char*)lBl[buf] + t * 4096 + tid * 16);
    }
  };

  f32x4 acc[4][4] = {};

  stage(0, 0);
  stage(1, 1);   // 16 VMEM in flight

  for (int kt = 0; kt < NT; ++kt) {
    const int cur = kt & 1;
    // own cur-tile DMAs retired (leave next tile's 8 in flight), then
    // barrier so ALL waves' cur-tile DMAs have landed.
    __builtin_amdgcn_sched_barrier(0);
    if (kt < NT - 1) asm volatile("s_waitcnt vmcnt(8)" ::: "memory");
    else             asm volatile("s_waitcnt vmcnt(0)" ::: "memory");
    __builtin_amdgcn_s_barrier();
    __builtin_amdgcn_sched_barrier(0);

    bf16x8 ah[4], al[4], bh[4], bl[4];
#pragma unroll
    for (int i = 0; i < 4; ++i) {
      const int R = wr * 64 + i * 16 + l16;
      const float4 f0 = *(const float4*)&lA[cur][R * 32 + ((2 * quad - R) & 7) * 4];
      const float4 f1 = *(const float4*)&lA[cur][R * 32 + ((2 * quad + 1 - R) & 7) * 4];
      uint4 h, l;
      split2_pk(f0.x, f0.y, h.x, l.x); split2_pk(f0.z, f0.w, h.y, l.y);
      split2_pk(f1.x, f1.y, h.z, l.z); split2_pk(f1.z, f1.w, h.w, l.w);
      ah[i] = __builtin_bit_cast(bf16x8, h);
      al[i] = __builtin_bit_cast(bf16x8, l);
    }
#pragma unroll
    for (int j = 0; j < 4; ++j) {
      const int R = wc * 64 + j * 16 + l16;
      const int c = (quad - (R >> 1)) & 3;
      bh[j] = *(const bf16x8*)&lBh[cur][R * 32 + c * 8];
      bl[j] = *(const bf16x8*)&lBl[cur][R * 32 + c * 8];
    }
    __builtin_amdgcn_s_setprio(1);
#pragma unroll
    for (int i = 0; i < 4; ++i)
#pragma unroll
      for (int j = 0; j < 4; ++j) {
        acc[i][j] = __builtin_amdgcn_mfma_f32_16x16x32_bf16(ah[i], bh[j], acc[i][j], 0, 0, 0);
        acc[i][j] = __builtin_amdgcn_mfma_f32_16x16x32_bf16(ah[i], bl[j], acc[i][j], 0, 0, 0);
        acc[i][j] = __builtin_amdgcn_mfma_f32_16x16x32_bf16(al[i], bh[j], acc[i][j], 0, 0, 0);
      }
    __builtin_amdgcn_s_setprio(0);

    // all waves done READING cur, then restage into cur's buffer;
    // its loads fly across the next barrier.
    __builtin_amdgcn_sched_barrier(0);
    __builtin_amdgcn_s_barrier();
    __builtin_amdgcn_sched_barrier(0);
    if (kt + 2 < NT) stage(cur, kt + 2);
  }

  // epilogue: C/D layout col=lane&15 (N), row=quad*4+reg (M)
#pragma unroll
  for (int i = 0; i < 4; ++i)
#pragma unroll
    for (int j = 0; j < 4; ++j) {
      const int gn = n0 + wc * 64 + j * 16 + l16;
      const float bv = (z == 0) ? bias[gn - batch * 512] : 0.0f;
#pragma unroll
      for (int r = 0; r < 4; ++r) {
        const int gm = m0 + wr * 64 + i * 16 + quad * 4 + r;
        hp[(size_t)gm * NC + gn] = acc[i][j][r] + bv;
      }
    }
}

// =====================================================================
// GEMM2: lg = S1 @ H2^T + ga ; pre-split bf16 operands.
// Counted-vmcnt pipeline + fused colpart epilogue + ga reg-prefetch
// under the last MFMA cluster (T14). grid (32, 32), block 256, 64 KB LDS.
// =====================================================================
__global__ __launch_bounds__(256) void gemm2_k(
    const u16* __restrict__ AH, const u16* __restrict__ AL,
    const u16* __restrict__ BH, const u16* __restrict__ BL,
    const float* __restrict__ ga, float* __restrict__ C,
    float* __restrict__ pm, float* __restrict__ ps)
{
  constexpr int K = 512, N = 4096, NT = K / 32;
  __shared__ __align__(16) u16 lAh[2][128 * 32];
  __shared__ __align__(16) u16 lAl[2][128 * 32];
  __shared__ __align__(16) u16 lBh[2][128 * 32];
  __shared__ __align__(16) u16 lBl[2][128 * 32];

  const int tid  = threadIdx.x;
  const int lane = tid & 63;
  const int wave = tid >> 6;
  const int wr   = wave >> 1, wc = wave & 1;
  const int quad = lane >> 4;
  const int l16  = lane & 15;

  const int m0 = blockIdx.x * 128;
  const int n0 = blockIdx.y * 128;

  const int rB = tid >> 2, cB = tid & 3;

  auto stage = [&](int buf, int kt) {   // 8 VMEM instrs per wave
    const int ko = kt * 32;
#pragma unroll
    for (int t = 0; t < 2; ++t) {
      const int r  = t * 64 + rB;
      const int cs = (cB + (r >> 1)) & 3;
      const size_t goA = (size_t)(m0 + r) * K + ko + cs * 8;
      const size_t goB = (size_t)(n0 + r) * K + ko + cs * 8;
      gload_lds16(AH + goA, (char*)lAh[buf] + t * 4096 + tid * 16);
      gload_lds16(AL + goA, (char*)lAl[buf] + t * 4096 + tid * 16);
      gload_lds16(BH + goB, (char*)lBh[buf] + t * 4096 + tid * 16);
      gload_lds16(BL + goB, (char*)lBl[buf] + t * 4096 + tid * 16);
    }
  };

  f32x4 acc[4][4] = {};
  float ga_r[4][4][4];   // prefetched ga values (loaded in last K-iter)

  stage(0, 0);
  stage(1, 1);

  for (int kt = 0; kt < NT; ++kt) {
    const int cur = kt & 1;
    __builtin_amdgcn_sched_barrier(0);
    if (kt < NT - 1) asm volatile("s_waitcnt vmcnt(8)" ::: "memory");
    else             asm volatile("s_waitcnt vmcnt(0)" ::: "memory");
    __builtin_amdgcn_s_barrier();
    __builtin_amdgcn_sched_barrier(0);

    // last iteration: issue ga loads now; latency hides under the MFMA below
    if (kt == NT - 1) {
#pragma unroll
      for (int i = 0; i < 4; ++i)
#pragma unroll
        for (int j = 0; j < 4; ++j) {
          const int gn = n0 + wc * 64 + j * 16 + l16;
#pragma unroll
          for (int r = 0; r < 4; ++r) {
            const int gm = m0 + wr * 64 + i * 16 + quad * 4 + r;
            ga_r[i][j][r] = ga[(size_t)gm * N + gn];
          }
        }
    }

    bf16x8 ah[4], al[4], bh[4], bl[4];
#pragma unroll
    for (int i = 0; i < 4; ++i) {
      const int R = wr * 64 + i * 16 + l16;
      const int c = (quad - (R >> 1)) & 3;
      ah[i] = *(const bf16x8*)&lAh[cur][R * 32 + c * 8];
      al[i] = *(const bf16x8*)&lAl[cur][R * 32 + c * 8];
    }
#pragma unroll
    for (int j = 0; j < 4; ++j) {
      const int R = wc * 64 + j * 16 + l16;
      const int c = (quad - (R >> 1)) & 3;
      bh[j] = *(const bf16x8*)&lBh[cur][R * 32 + c * 8];
      bl[j] = *(const bf16x8*)&lBl[cur][R * 32 + c * 8];
    }
    __builtin_amdgcn_s_setprio(1);
#pragma unroll
    for (int i = 0; i < 4; ++i)
#pragma unroll
      for (int j = 0; j < 4; ++j) {
        acc[i][j] = __builtin_amdgcn_mfma_f32_16x16x32_bf16(ah[i], bh[j], acc[i][j], 0, 0, 0);
        acc[i][j] = __builtin_amdgcn_mfma_f32_16x16x32_bf16(ah[i], bl[j], acc[i][j], 0, 0, 0);
        acc[i][j] = __builtin_amdgcn_mfma_f32_16x16x32_bf16(al[i], bh[j], acc[i][j], 0, 0, 0);
      }
    __builtin_amdgcn_s_setprio(0);

    __builtin_amdgcn_sched_barrier(0);
    __builtin_amdgcn_s_barrier();
    __builtin_amdgcn_sched_barrier(0);
    if (kt + 2 < NT) stage(cur, kt + 2);
  }
  // (final loop barrier passed: staging LDS is dead, reusable as scratch)

  // epilogue: lg = acc + ga -> C; keep v in acc for column reduction
#pragma unroll
  for (int i = 0; i < 4; ++i)
#pragma unroll
    for (int j = 0; j < 4; ++j) {
      const int gn = n0 + wc * 64 + j * 16 + l16;
#pragma unroll
      for (int r = 0; r < 4; ++r) {
        const int gm = m0 + wr * 64 + i * 16 + quad * 4 + r;
        const size_t idx = (size_t)gm * N + gn;
        const float v = acc[i][j][r] + ga_r[i][j][r];
        C[idx] = v;
        acc[i][j][r] = v;
      }
    }

  // fused colpart: per-column (max, expsum) over this block's 128 rows.
  float* red = (float*)lAh;   // scratch [2(wr)][128 col][2]
#pragma unroll
  for (int j = 0; j < 4; ++j) {
    float m = -3.0e38f;
#pragma unroll
    for (int i = 0; i < 4; ++i)
#pragma unroll
      for (int r = 0; r < 4; ++r) m = fmaxf(m, acc[i][j][r]);
    float s = 0.f;
#pragma unroll
    for (int i = 0; i < 4; ++i)
#pragma unroll
      for (int r = 0; r < 4; ++r) s += __expf(acc[i][j][r] - m);
    // combine across the 4 quads (same l16 -> same column)
#pragma unroll
    for (int off = 16; off <= 32; off <<= 1) {
      const float mo = __shfl_xor(m, off);
      const float so = __shfl_xor(s, off);
      const float mn = fmaxf(m, mo);
      s = s * __expf(m - mn) + so * __expf(mo - mn);
      m = mn;
    }
    if (quad == 0) {
      const int col = wc * 64 + j * 16 + l16;
      red[(wr * 128 + col) * 2 + 0] = m;
      red[(wr * 128 + col) * 2 + 1] = s;
    }
  }
  __syncthreads();
  if (tid < 128) {
    const float ma = red[(0 * 128 + tid) * 2 + 0], sa = red[(0 * 128 + tid) * 2 + 1];
    const float mb = red[(1 * 128 + tid) * 2 + 0], sb = red[(1 * 128 + tid) * 2 + 1];
    const float mm = fmaxf(ma, mb);
    const float ss = sa * __expf(ma - mm) + sb * __expf(mb - mm);
    pm[(size_t)blockIdx.x * N + n0 + tid] = mm;
    ps[(size_t)blockIdx.x * N + n0 + tid] = ss;
  }
}

// =====================================================================
// R9: bandsum + h2split merged into ONE launch (bodies unchanged).
// bx < M/8 (512): bandsum block (ROWS=16, cols via (bx&1)*256+tid).
// bx >= M/8 (128 blocks): h2split, 32 rows each, 2 rows per thread-half.
// =====================================================================
__global__ __launch_bounds__(256) void bandh2_kernel(
    const float* __restrict__ hp0, const float* __restrict__ hp1,
    u16* __restrict__ sh, u16* __restrict__ sl,
    u16* __restrict__ hh, u16* __restrict__ hl, int M)
{
  const int bx  = blockIdx.x;
  const int tid = threadIdx.x;
  if (bx < M / 8) {
    // ---- bandsum: sliding-window(127) row-sum of h1 cols [0,512) ----
    const int c = (bx & 1) * 256 + tid;   // 0..511
    const int R = (bx >> 1) * 16;
    float s = 0.f;
    for (int k = R - 63; k < R + 63; ++k)
      if (k >= 0 && k < M) {
        const size_t o = (size_t)k * 1024 + c;
        s += hp0[o] + hp1[o];
      }
    for (int i = R; i < R + 16; ++i) {
      const int ka = i + 63;
      if (ka < M) {
        const size_t o = (size_t)ka * 1024 + c;
        s += hp0[o] + hp1[o];
      }
      const u16 hb = f2bf(s);
      sh[(size_t)i * 512 + c] = hb;
      sl[(size_t)i * 512 + c] = f2bf(s - bf2f(hb));
      const int kr = i - 63;
      if (kr >= 0) {
        const size_t o = (size_t)kr * 1024 + c;
        s -= hp0[o] + hp1[o];
      }
    }
  } else {
    // ---- h2split: h2 = sum(hp0,hp1) cols [512,1024) -> split bf16 ----
    const int b    = bx - M / 8;        // 0..127
    const int row0 = b * 32;
    const int c4   = (tid & 127) * 4;
    const int half = tid >> 7;
#pragma unroll
    for (int rr = 0; rr < 16; ++rr) {
      const size_t row = row0 + rr * 2 + half;
      const size_t o = row * 1024 + 512 + c4;
      const float4 a  = *(const float4*)&hp0[o];
      const float4 b4 = *(const float4*)&hp1[o];
      uint2 hp_, lp_;
      split2(a.x + b4.x, a.y + b4.y, hp_.x, lp_.x);
      split2(a.z + b4.z, a.w + b4.w, hp_.y, lp_.y);
      *(uint2*)&hh[row * 512 + c4] = hp_;
      *(uint2*)&hl[row * 512 + c4] = lp_;
    }
  }
}

// ---------- column softmax combine + normalize ----------
__global__ __launch_bounds__(256) void colcombine_kernel(
    const float* __restrict__ pm, const float* __restrict__ ps,
    float* __restrict__ cv, int N, int nb)
{
  const int j = blockIdx.x * 256 + threadIdx.x;
  float m = -3.0e38f;
  for (int b = 0; b < nb; ++b) m = fmaxf(m, pm[(size_t)b * N + j]);
  float s = 0.f;
  for (int b = 0; b < nb; ++b) s += ps[(size_t)b * N + j] * __expf(pm[(size_t)b * N + j] - m);
  cv[j] = m + __logf(s);
}

__global__ __launch_bounds__(256) void norm_kernel(
    float* __restrict__ lg, const float* __restrict__ cv, int N)
{
  const size_t t = (size_t)blockIdx.x * 256 + threadIdx.x;
  float4 v = ((const float4*)lg)[t];
  const int j4 = (int)(t % (size_t)(N / 4));
  const float4 c = ((const float4*)cv)[j4];
  float4 o;
  o.x = __expf(v.x - c.x);
  o.y = __expf(v.y - c.y);
  o.z = __expf(v.z - c.z);
  o.w = __expf(v.w - c.w);
  ((float4*)lg)[t] = o;
}

extern "C" void kernel_launch(void* const* d_in, const int* in_sizes, int n_in,
                              void* d_out, int out_size, void* d_ws, size_t ws_size,
                              hipStream_t stream)
{
  const float* x1 = (const float*)d_in[0];
  const float* x2 = (const float*)d_in[1];
  const float* W1 = (const float*)d_in[2];
  const float* b1 = (const float*)d_in[3];
  const float* W2 = (const float*)d_in[4];
  const float* b2 = (const float*)d_in[5];
  const float* ga = (const float*)d_in[6];
  float* out = (float*)d_out;

  const int T = 4096, E = 512;

  // split-K=2 partials live in d_out (2 x 16 MB, dead before lg lands)
  float* hp0 = out;
  float* hp1 = out + (size_t)T * 1024;

  char* w = (char*)d_ws;
  u16* WH  = (u16*)w;  w += (size_t)2 * E * T * 2;   // stacked (1024 x 4096)
  u16* WL  = (u16*)w;  w += (size_t)2 * E * T * 2;
  u16* S1H = (u16*)w;  w += (size_t)T * E * 2;
  u16* S1L = (u16*)w;  w += (size_t)T * E * 2;
  u16* H2H = (u16*)w;  w += (size_t)T * E * 2;
  u16* H2L = (u16*)w;  w += (size_t)T * E * 2;
  float* pm = (float*)w; w += (size_t)32 * T * 4;
  float* ps = (float*)w; w += (size_t)32 * T * 4;
  float* cv = (float*)w; w += (size_t)T * 4;

  // pre-split W1+W2 into stacked WH/WL (rows 0-511 = W1, 512-1023 = W2)
  splitW_kernel<<<E * T / 512, 256, 0, stream>>>(W1, W2, WH, WL, E * T / 4);

  // h partials (4096 x 1024), split-K=2
  gemm1_k<<<dim3(T / 128, 8, 2), 256, 0, stream>>>(
      x1, x2, WH, WL, b1, b2, hp0, hp1);

  // S1 = band-sum(h1) -> split; h2 -> split (one launch)
  bandh2_kernel<<<T / 8 + T / 32, 256, 0, stream>>>(
      hp0, hp1, S1H, S1L, H2H, H2L, T);

  // lg = S1 @ h2^T + global_att (into d_out) + fused column partials
  gemm2_k<<<dim3(T / 128, T / 128), 256, 0, stream>>>(
      S1H, S1L, H2H, H2L, ga, out, pm, ps);

  // softmax over axis 0 (combine + normalize)
  colcombine_kernel<<<T / 256, 256, 0, stream>>>(pm, ps, cv, T, 32);
  norm_kernel<<<T * T / 1024, 256, 0, stream>>>(out, cv, T);
}

// Round 11
// 440.507 us; speedup vs baseline: 1.0057x; 1.0057x over previous
//
#include <hip/hip_runtime.h>

typedef unsigned short u16;
using f32x4  = __attribute__((ext_vector_type(4))) float;
using bf16x8 = __attribute__((ext_vector_type(8))) __bf16;

// ---------- bf16 helpers ----------
__device__ __forceinline__ u16 f2bf(float f) {
  unsigned u = __builtin_bit_cast(unsigned, f);
  u += 0x7FFFu + ((u >> 16) & 1u);
  return (u16)(u >> 16);
}
__device__ __forceinline__ float bf2f(u16 h) {
  unsigned u = ((unsigned)h) << 16;
  return __builtin_bit_cast(float, u);
}

// two floats -> packed (hi bf16x2, lo bf16x2); RNE hi, trunc lo.
__device__ __forceinline__ void split2(float f0, float f1, unsigned& hi, unsigned& lo) {
  unsigned u0 = __builtin_bit_cast(unsigned, f0);
  unsigned u1 = __builtin_bit_cast(unsigned, f1);
  unsigned r0 = u0 + (0x7FFFu + ((u0 >> 16) & 1u));
  unsigned r1 = u1 + (0x7FFFu + ((u1 >> 16) & 1u));
  hi = (r0 >> 16) | (r1 & 0xFFFF0000u);
  float h0 = __builtin_bit_cast(float, r0 & 0xFFFF0000u);
  float h1 = __builtin_bit_cast(float, r1 & 0xFFFF0000u);
  unsigned l0 = __builtin_bit_cast(unsigned, f0 - h0);
  unsigned l1 = __builtin_bit_cast(unsigned, f1 - h1);
  lo = (l0 >> 16) | (l1 & 0xFFFF0000u);
}

// cvt_pk-based split (R5): 6 VALU ops vs ~11. hi = RNE pair; lo = RNE residual.
__device__ __forceinline__ void split2_pk(float f0, float f1, unsigned& hi, unsigned& lo) {
  unsigned h;
  asm("v_cvt_pk_bf16_f32 %0, %1, %2" : "=v"(h) : "v"(f0), "v"(f1));
  const float h0 = __builtin_bit_cast(float, h << 16);
  const float h1 = __builtin_bit_cast(float, h & 0xFFFF0000u);
  unsigned l;
  asm("v_cvt_pk_bf16_f32 %0, %1, %2" : "=v"(l) : "v"(f0 - h0), "v"(f1 - h1));
  hi = h; lo = l;
}

// async global->LDS, 16B/lane; LDS dest MUST be wave-uniform base + lane*16
__device__ __forceinline__ void gload_lds16(const void* g, void* l) {
  __builtin_amdgcn_global_load_lds((__attribute__((address_space(1))) void*)g,
                                   (__attribute__((address_space(3))) void*)l,
                                   16, 0, 0);
}

// ---------- split W1+W2 -> stacked (bf16 hi, bf16 lo); R10: grid-stride ----------
__global__ __launch_bounds__(256) void splitW_kernel(
    const float* __restrict__ W1, const float* __restrict__ W2,
    u16* __restrict__ hi, u16* __restrict__ lo, int n4each)
{
  const size_t total = 2 * (size_t)n4each;
  for (size_t t = (size_t)blockIdx.x * 256 + threadIdx.x; t < total;
       t += (size_t)gridDim.x * 256) {
    const float4 v = (t < (size_t)n4each) ? ((const float4*)W1)[t]
                                          : ((const float4*)W2)[t - n4each];
    uint2 hp, lp;
    split2(v.x, v.y, hp.x, lp.x);
    split2(v.z, v.w, hp.y, lp.y);
    ((uint2*)hi)[t] = hp;
    ((uint2*)lo)[t] = lp;
  }
}

// =====================================================================
// GEMM1: h[:,0:512]=x1@W1^T+b1, h[:,512:1024]=x2@W2^T+b2 (W stacked 1024xK)
// split-K=2 (R8), 2x2 wave layout, split2_pk, counted-vmcnt (T4) +
// setprio (T5), double-buffered 64 KB LDS. grid (32,8,2), block 256.
// =====================================================================
__global__ __launch_bounds__(256) void gemm1_k(
    const float* __restrict__ x1, const float* __restrict__ x2,
    const u16* __restrict__ WH, const u16* __restrict__ WL,
    const float* __restrict__ b1, const float* __restrict__ b2,
    float* __restrict__ hp0, float* __restrict__ hp1)
{
  constexpr int K = 4096, NC = 1024, KC = 2048, NT = KC / 32;
  __shared__ __align__(16) float lA[2][128 * 32];   // 16 KB x2
  __shared__ __align__(16) u16 lBh[2][128 * 32];    // 8 KB x2
  __shared__ __align__(16) u16 lBl[2][128 * 32];    // 8 KB x2

  const int tid  = threadIdx.x;
  const int lane = tid & 63;
  const int wave = tid >> 6;
  const int wr   = wave >> 1, wc = wave & 1;   // 2x2: wave owns 64x64
  const int quad = lane >> 4;
  const int l16  = lane & 15;

  const int m0    = blockIdx.x * 128;
  const int n0    = blockIdx.y * 128;
  const int batch = (n0 >= 512);
  const float* Ag   = batch ? x2 : x1;
  const float* bias = batch ? b2 : b1;
  const int z = blockIdx.z;
  float* hp = (z == 0) ? hp0 : hp1;
  const int k00 = z * KC;

  // staging maps (LDS dest linear in tid*16 -> DMA-legal)
  const int rA = tid >> 3, cA = tid & 7;  // A: 4 rounds x 32 rows, 8 chunks/row
  const int rB = tid >> 2, cB = tid & 3;  // B: 2 rounds x 64 rows, 4 chunks/row

  auto stage = [&](int buf, int kt) {   // 8 VMEM instrs per wave
    const int ko = k00 + kt * 32;
#pragma unroll
    for (int t = 0; t < 4; ++t) {
      const int r  = t * 32 + rA;
      const int cs = (cA + r) & 7;                 // source-chunk swizzle
      gload_lds16(Ag + (size_t)(m0 + r) * K + ko + cs * 4,
                  (char*)lA[buf] + t * 4096 + tid * 16);
    }
#pragma unroll
    for (int t = 0; t < 2; ++t) {
      const int r  = t * 64 + rB;
      const int cs = (cB + (r >> 1)) & 3;
      gload_lds16(WH + (size_t)(n0 + r) * K + ko + cs * 8,
                  (char*)lBh[buf] + t * 4096 + tid * 16);
      gload_lds16(WL + (size_t)(n0 + r) * K + ko + cs * 8,
                  (char*)lBl[buf] + t * 4096 + tid * 16);
    }
  };

  f32x4 acc[4][4] = {};

  stage(0, 0);
  stage(1, 1);   // 16 VMEM in flight

  for (int kt = 0; kt < NT; ++kt) {
    const int cur = kt & 1;
    // own cur-tile DMAs retired (leave next tile's 8 in flight), then
    // barrier so ALL waves' cur-tile DMAs have landed.
    __builtin_amdgcn_sched_barrier(0);
    if (kt < NT - 1) asm volatile("s_waitcnt vmcnt(8)" ::: "memory");
    else             asm volatile("s_waitcnt vmcnt(0)" ::: "memory");
    __builtin_amdgcn_s_barrier();
    __builtin_amdgcn_sched_barrier(0);

    bf16x8 ah[4], al[4], bh[4], bl[4];
#pragma unroll
    for (int i = 0; i < 4; ++i) {
      const int R = wr * 64 + i * 16 + l16;
      const float4 f0 = *(const float4*)&lA[cur][R * 32 + ((2 * quad - R) & 7) * 4];
      const float4 f1 = *(const float4*)&lA[cur][R * 32 + ((2 * quad + 1 - R) & 7) * 4];
      uint4 h, l;
      split2_pk(f0.x, f0.y, h.x, l.x); split2_pk(f0.z, f0.w, h.y, l.y);
      split2_pk(f1.x, f1.y, h.z, l.z); split2_pk(f1.z, f1.w, h.w, l.w);
      ah[i] = __builtin_bit_cast(bf16x8, h);
      al[i] = __builtin_bit_cast(bf16x8, l);
    }
#pragma unroll
    for (int j = 0; j < 4; ++j) {
      const int R = wc * 64 + j * 16 + l16;
      const int c = (quad - (R >> 1)) & 3;
      bh[j] = *(const bf16x8*)&lBh[cur][R * 32 + c * 8];
      bl[j] = *(const bf16x8*)&lBl[cur][R * 32 + c * 8];
    }
    __builtin_amdgcn_s_setprio(1);
#pragma unroll
    for (int i = 0; i < 4; ++i)
#pragma unroll
      for (int j = 0; j < 4; ++j) {
        acc[i][j] = __builtin_amdgcn_mfma_f32_16x16x32_bf16(ah[i], bh[j], acc[i][j], 0, 0, 0);
        acc[i][j] = __builtin_amdgcn_mfma_f32_16x16x32_bf16(ah[i], bl[j], acc[i][j], 0, 0, 0);
        acc[i][j] = __builtin_amdgcn_mfma_f32_16x16x32_bf16(al[i], bh[j], acc[i][j], 0, 0, 0);
      }
    __builtin_amdgcn_s_setprio(0);

    // all waves done READING cur, then restage into cur's buffer;
    // its loads fly across the next barrier.
    __builtin_amdgcn_sched_barrier(0);
    __builtin_amdgcn_s_barrier();
    __builtin_amdgcn_sched_barrier(0);
    if (kt + 2 < NT) stage(cur, kt + 2);
  }

  // epilogue: C/D layout col=lane&15 (N), row=quad*4+reg (M)
#pragma unroll
  for (int i = 0; i < 4; ++i)
#pragma unroll
    for (int j = 0; j < 4; ++j) {
      const int gn = n0 + wc * 64 + j * 16 + l16;
      const float bv = (z == 0) ? bias[gn - batch * 512] : 0.0f;
#pragma unroll
      for (int r = 0; r < 4; ++r) {
        const int gm = m0 + wr * 64 + i * 16 + quad * 4 + r;
        hp[(size_t)gm * NC + gn] = acc[i][j][r] + bv;
      }
    }
}

// =====================================================================
// GEMM2: lg = S1 @ H2^T + ga ; pre-split bf16 operands.
// Counted-vmcnt pipeline + fused colpart epilogue + ga reg-prefetch
// under the last MFMA cluster (T14). grid (32, 32), block 256, 64 KB LDS.
// =====================================================================
__global__ __launch_bounds__(256) void gemm2_k(
    const u16* __restrict__ AH, const u16* __restrict__ AL,
    const u16* __restrict__ BH, const u16* __restrict__ BL,
    const float* __restrict__ ga, float* __restrict__ C,
    float* __restrict__ pm, float* __restrict__ ps)
{
  constexpr int K = 512, N = 4096, NT = K / 32;
  __shared__ __align__(16) u16 lAh[2][128 * 32];
  __shared__ __align__(16) u16 lAl[2][128 * 32];
  __shared__ __align__(16) u16 lBh[2][128 * 32];
  __shared__ __align__(16) u16 lBl[2][128 * 32];

  const int tid  = threadIdx.x;
  const int lane = tid & 63;
  const int wave = tid >> 6;
  const int wr   = wave >> 1, wc = wave & 1;
  const int quad = lane >> 4;
  const int l16  = lane & 15;

  const int m0 = blockIdx.x * 128;
  const int n0 = blockIdx.y * 128;

  const int rB = tid >> 2, cB = tid & 3;

  auto stage = [&](int buf, int kt) {   // 8 VMEM instrs per wave
    const int ko = kt * 32;
#pragma unroll
    for (int t = 0; t < 2; ++t) {
      const int r  = t * 64 + rB;
      const int cs = (cB + (r >> 1)) & 3;
      const size_t goA = (size_t)(m0 + r) * K + ko + cs * 8;
      const size_t goB = (size_t)(n0 + r) * K + ko + cs * 8;
      gload_lds16(AH + goA, (char*)lAh[buf] + t * 4096 + tid * 16);
      gload_lds16(AL + goA, (char*)lAl[buf] + t * 4096 + tid * 16);
      gload_lds16(BH + goB, (char*)lBh[buf] + t * 4096 + tid * 16);
      gload_lds16(BL + goB, (char*)lBl[buf] + t * 4096 + tid * 16);
    }
  };

  f32x4 acc[4][4] = {};
  float ga_r[4][4][4];   // prefetched ga values (loaded in last K-iter)

  stage(0, 0);
  stage(1, 1);

  for (int kt = 0; kt < NT; ++kt) {
    const int cur = kt & 1;
    __builtin_amdgcn_sched_barrier(0);
    if (kt < NT - 1) asm volatile("s_waitcnt vmcnt(8)" ::: "memory");
    else             asm volatile("s_waitcnt vmcnt(0)" ::: "memory");
    __builtin_amdgcn_s_barrier();
    __builtin_amdgcn_sched_barrier(0);

    // last iteration: issue ga loads now; latency hides under the MFMA below
    if (kt == NT - 1) {
#pragma unroll
      for (int i = 0; i < 4; ++i)
#pragma unroll
        for (int j = 0; j < 4; ++j) {
          const int gn = n0 + wc * 64 + j * 16 + l16;
#pragma unroll
          for (int r = 0; r < 4; ++r) {
            const int gm = m0 + wr * 64 + i * 16 + quad * 4 + r;
            ga_r[i][j][r] = ga[(size_t)gm * N + gn];
          }
        }
    }

    bf16x8 ah[4], al[4], bh[4], bl[4];
#pragma unroll
    for (int i = 0; i < 4; ++i) {
      const int R = wr * 64 + i * 16 + l16;
      const int c = (quad - (R >> 1)) & 3;
      ah[i] = *(const bf16x8*)&lAh[cur][R * 32 + c * 8];
      al[i] = *(const bf16x8*)&lAl[cur][R * 32 + c * 8];
    }
#pragma unroll
    for (int j = 0; j < 4; ++j) {
      const int R = wc * 64 + j * 16 + l16;
      const int c = (quad - (R >> 1)) & 3;
      bh[j] = *(const bf16x8*)&lBh[cur][R * 32 + c * 8];
      bl[j] = *(const bf16x8*)&lBl[cur][R * 32 + c * 8];
    }
    __builtin_amdgcn_s_setprio(1);
#pragma unroll
    for (int i = 0; i < 4; ++i)
#pragma unroll
      for (int j = 0; j < 4; ++j) {
        acc[i][j] = __builtin_amdgcn_mfma_f32_16x16x32_bf16(ah[i], bh[j], acc[i][j], 0, 0, 0);
        acc[i][j] = __builtin_amdgcn_mfma_f32_16x16x32_bf16(ah[i], bl[j], acc[i][j], 0, 0, 0);
        acc[i][j] = __builtin_amdgcn_mfma_f32_16x16x32_bf16(al[i], bh[j], acc[i][j], 0, 0, 0);
      }
    __builtin_amdgcn_s_setprio(0);

    __builtin_amdgcn_sched_barrier(0);
    __builtin_amdgcn_s_barrier();
    __builtin_amdgcn_sched_barrier(0);
    if (kt + 2 < NT) stage(cur, kt + 2);
  }
  // (final loop barrier passed: staging LDS is dead, reusable as scratch)

  // epilogue: lg = acc + ga -> C; keep v in acc for column reduction
#pragma unroll
  for (int i = 0; i < 4; ++i)
#pragma unroll
    for (int j = 0; j < 4; ++j) {
      const int gn = n0 + wc * 64 + j * 16 + l16;
#pragma unroll
      for (int r = 0; r < 4; ++r) {
        const int gm = m0 + wr * 64 + i * 16 + quad * 4 + r;
        const size_t idx = (size_t)gm * N + gn;
        const float v = acc[i][j][r] + ga_r[i][j][r];
        C[idx] = v;
        acc[i][j][r] = v;
      }
    }

  // fused colpart: per-column (max, expsum) over this block's 128 rows.
  float* red = (float*)lAh;   // scratch [2(wr)][128 col][2]
#pragma unroll
  for (int j = 0; j < 4; ++j) {
    float m = -3.0e38f;
#pragma unroll
    for (int i = 0; i < 4; ++i)
#pragma unroll
      for (int r = 0; r < 4; ++r) m = fmaxf(m, acc[i][j][r]);
    float s = 0.f;
#pragma unroll
    for (int i = 0; i < 4; ++i)
#pragma unroll
      for (int r = 0; r < 4; ++r) s += __expf(acc[i][j][r] - m);
    // combine across the 4 quads (same l16 -> same column)
#pragma unroll
    for (int off = 16; off <= 32; off <<= 1) {
      const float mo = __shfl_xor(m, off);
      const float so = __shfl_xor(s, off);
      const float mn = fmaxf(m, mo);
      s = s * __expf(m - mn) + so * __expf(mo - mn);
      m = mn;
    }
    if (quad == 0) {
      const int col = wc * 64 + j * 16 + l16;
      red[(wr * 128 + col) * 2 + 0] = m;
      red[(wr * 128 + col) * 2 + 1] = s;
    }
  }
  __syncthreads();
  if (tid < 128) {
    const float ma = red[(0 * 128 + tid) * 2 + 0], sa = red[(0 * 128 + tid) * 2 + 1];
    const float mb = red[(1 * 128 + tid) * 2 + 0], sb = red[(1 * 128 + tid) * 2 + 1];
    const float mm = fmaxf(ma, mb);
    const float ss = sa * __expf(ma - mm) + sb * __expf(mb - mm);
    pm[(size_t)blockIdx.x * N + n0 + tid] = mm;
    ps[(size_t)blockIdx.x * N + n0 + tid] = ss;
  }
}

// =====================================================================
// bandsum + h2split in one launch (R9; bodies unchanged).
// bx < M/8 (512): bandsum block (ROWS=16, cols via (bx&1)*256+tid).
// bx >= M/8 (128 blocks): h2split, 32 rows each, 2 rows per thread-half.
// =====================================================================
__global__ __launch_bounds__(256) void bandh2_kernel(
    const float* __restrict__ hp0, const float* __restrict__ hp1,
    u16* __restrict__ sh, u16* __restrict__ sl,
    u16* __restrict__ hh, u16* __restrict__ hl, int M)
{
  const int bx  = blockIdx.x;
  const int tid = threadIdx.x;
  if (bx < M / 8) {
    // ---- bandsum: sliding-window(127) row-sum of h1 cols [0,512) ----
    const int c = (bx & 1) * 256 + tid;   // 0..511
    const int R = (bx >> 1) * 16;
    float s = 0.f;
    for (int k = R - 63; k < R + 63; ++k)
      if (k >= 0 && k < M) {
        const size_t o = (size_t)k * 1024 + c;
        s += hp0[o] + hp1[o];
      }
    for (int i = R; i < R + 16; ++i) {
      const int ka = i + 63;
      if (ka < M) {
        const size_t o = (size_t)ka * 1024 + c;
        s += hp0[o] + hp1[o];
      }
      const u16 hb = f2bf(s);
      sh[(size_t)i * 512 + c] = hb;
      sl[(size_t)i * 512 + c] = f2bf(s - bf2f(hb));
      const int kr = i - 63;
      if (kr >= 0) {
        const size_t o = (size_t)kr * 1024 + c;
        s -= hp0[o] + hp1[o];
      }
    }
  } else {
    // ---- h2split: h2 = sum(hp0,hp1) cols [512,1024) -> split bf16 ----
    const int b    = bx - M / 8;        // 0..127
    const int row0 = b * 32;
    const int c4   = (tid & 127) * 4;
    const int half = tid >> 7;
#pragma unroll
    for (int rr = 0; rr < 16; ++rr) {
      const size_t row = row0 + rr * 2 + half;
      const size_t o = row * 1024 + 512 + c4;
      const float4 a  = *(const float4*)&hp0[o];
      const float4 b4 = *(const float4*)&hp1[o];
      uint2 hp_, lp_;
      split2(a.x + b4.x, a.y + b4.y, hp_.x, lp_.x);
      split2(a.z + b4.z, a.w + b4.w, hp_.y, lp_.y);
      *(uint2*)&hh[row * 512 + c4] = hp_;
      *(uint2*)&hl[row * 512 + c4] = lp_;
    }
  }
}

// ---------- column softmax combine + normalize ----------
__global__ __launch_bounds__(256) void colcombine_kernel(
    const float* __restrict__ pm, const float* __restrict__ ps,
    float* __restrict__ cv, int N, int nb)
{
  const int j = blockIdx.x * 256 + threadIdx.x;
  float m = -3.0e38f;
  for (int b = 0; b < nb; ++b) m = fmaxf(m, pm[(size_t)b * N + j]);
  float s = 0.f;
  for (int b = 0; b < nb; ++b) s += ps[(size_t)b * N + j] * __expf(pm[(size_t)b * N + j] - m);
  cv[j] = m + __logf(s);
}

// R10: grid-stride (2048 blocks, ~8/CU) instead of 16384 one-shot blocks.
__global__ __launch_bounds__(256) void norm_kernel(
    float* __restrict__ lg, const float* __restrict__ cv, int N, size_t total4)
{
  for (size_t t = (size_t)blockIdx.x * 256 + threadIdx.x; t < total4;
       t += (size_t)gridDim.x * 256) {
    float4 v = ((const float4*)lg)[t];
    const int j4 = (int)(t % (size_t)(N / 4));
    const float4 c = ((const float4*)cv)[j4];
    float4 o;
    o.x = __expf(v.x - c.x);
    o.y = __expf(v.y - c.y);
    o.z = __expf(v.z - c.z);
    o.w = __expf(v.w - c.w);
    ((float4*)lg)[t] = o;
  }
}

extern "C" void kernel_launch(void* const* d_in, const int* in_sizes, int n_in,
                              void* d_out, int out_size, void* d_ws, size_t ws_size,
                              hipStream_t stream)
{
  const float* x1 = (const float*)d_in[0];
  const float* x2 = (const float*)d_in[1];
  const float* W1 = (const float*)d_in[2];
  const float* b1 = (const float*)d_in[3];
  const float* W2 = (const float*)d_in[4];
  const float* b2 = (const float*)d_in[5];
  const float* ga = (const float*)d_in[6];
  float* out = (float*)d_out;

  const int T = 4096, E = 512;

  // split-K=2 partials live in d_out (2 x 16 MB, dead before lg lands)
  float* hp0 = out;
  float* hp1 = out + (size_t)T * 1024;

  char* w = (char*)d_ws;
  u16* WH  = (u16*)w;  w += (size_t)2 * E * T * 2;   // stacked (1024 x 4096)
  u16* WL  = (u16*)w;  w += (size_t)2 * E * T * 2;
  u16* S1H = (u16*)w;  w += (size_t)T * E * 2;
  u16* S1L = (u16*)w;  w += (size_t)T * E * 2;
  u16* H2H = (u16*)w;  w += (size_t)T * E * 2;
  u16* H2L = (u16*)w;  w += (size_t)T * E * 2;
  float* pm = (float*)w; w += (size_t)32 * T * 4;
  float* ps = (float*)w; w += (size_t)32 * T * 4;
  float* cv = (float*)w; w += (size_t)T * 4;

  // pre-split W1+W2 into stacked WH/WL (rows 0-511 = W1, 512-1023 = W2)
  splitW_kernel<<<2048, 256, 0, stream>>>(W1, W2, WH, WL, E * T / 4);

  // h partials (4096 x 1024), split-K=2
  gemm1_k<<<dim3(T / 128, 8, 2), 256, 0, stream>>>(
      x1, x2, WH, WL, b1, b2, hp0, hp1);

  // S1 = band-sum(h1) -> split; h2 -> split (one launch)
  bandh2_kernel<<<T / 8 + T / 32, 256, 0, stream>>>(
      hp0, hp1, S1H, S1L, H2H, H2L, T);

  // lg = S1 @ h2^T + global_att (into d_out) + fused column partials
  gemm2_k<<<dim3(T / 128, T / 128), 256, 0, stream>>>(
      S1H, S1L, H2H, H2L, ga, out, pm, ps);

  // softmax over axis 0 (combine + normalize)
  colcombine_kernel<<<T / 256, 256, 0, stream>>>(pm, ps, cv, T, 32);
  norm_kernel<<<2048, 256, 0, stream>>>(out, cv, T, (size_t)T * T / 4);
}